// Round 1
// baseline (115.513 us; speedup 1.0000x reference)
//
#include <hip/hip_runtime.h>
#include <stdint.h>

// Sizes (fixed by the problem)
#define NCAP 64
#define NIMG 64
#define LTOK 64
#define RREG 36
#define EDIM 512
#define LAM 9.0f

typedef __attribute__((ext_vector_type(8))) short bf16x8;
typedef __attribute__((ext_vector_type(4))) float f32x4;
typedef __attribute__((ext_vector_type(8))) unsigned short u16x8;

__device__ __forceinline__ unsigned short f2bf(float f) {
  unsigned int u = __float_as_uint(f);
  u += 0x7FFFu + ((u >> 16) & 1u);   // RNE
  return (unsigned short)(u >> 16);
}

// L2-normalize rows of length 512. One wave per row. Writes bf16 (and
// optionally fp32) normalized output.
__global__ __launch_bounds__(256) void k_norm(const float* __restrict__ src,
                                              unsigned short* __restrict__ dbf,
                                              float* __restrict__ df32,
                                              int nvec) {
  int w = threadIdx.x >> 6, lane = threadIdx.x & 63;
  int v = blockIdx.x * 4 + w;
  if (v >= nvec) return;
  const float* p = src + (size_t)v * EDIM + lane * 8;
  float4 a = *(const float4*)p;
  float4 b = *(const float4*)(p + 4);
  float ss = a.x * a.x + a.y * a.y + a.z * a.z + a.w * a.w +
             b.x * b.x + b.y * b.y + b.z * b.z + b.w * b.w;
#pragma unroll
  for (int off = 1; off < 64; off <<= 1) ss += __shfl_xor(ss, off);
  float sc = 1.0f / fmaxf(sqrtf(ss), 1e-12f);
  float f0 = a.x * sc, f1 = a.y * sc, f2 = a.z * sc, f3 = a.w * sc;
  float f4 = b.x * sc, f5 = b.y * sc, f6 = b.z * sc, f7 = b.w * sc;
  u16x8 o = {f2bf(f0), f2bf(f1), f2bf(f2), f2bf(f3),
             f2bf(f4), f2bf(f5), f2bf(f6), f2bf(f7)};
  *(u16x8*)(dbf + (size_t)v * EDIM + lane * 8) = o;
  if (df32 != nullptr) {
    float* q = df32 + (size_t)v * EDIM + lane * 8;
    *(float4*)q = make_float4(f0, f1, f2, f3);
    *(float4*)(q + 4) = make_float4(f4, f5, f6, f7);
  }
}

// Per-image Gram matrix G[i] = img_n[i] @ img_n[i]^T  (36x36, fp32).
// 4 blocks per image (each does 324 of 1296 entries); img row-chunk staged
// in LDS in two e-passes (LDS 36x(256+4) floats = 37.4 KB).
#define GST 260
__global__ __launch_bounds__(256) void k_gram(const float* __restrict__ imgn,
                                              float* __restrict__ G) {
  __shared__ float si[RREG * GST];
  int i = blockIdx.x >> 2, q = blockIdx.x & 3;
  const float* base = imgn + (size_t)i * RREG * EDIM;
  float acc[2] = {0.f, 0.f};
  for (int pass = 0; pass < 2; ++pass) {
    __syncthreads();
    for (int t = threadIdx.x; t < RREG * 64; t += 256) {
      int row = t >> 6, e4 = t & 63;
      *(float4*)(si + row * GST + e4 * 4) =
          *(const float4*)(base + row * EDIM + pass * 256 + e4 * 4);
    }
    __syncthreads();
#pragma unroll
    for (int t = 0; t < 2; ++t) {
      int ofs = t * 256 + (int)threadIdx.x;
      if (ofs < 324) {
        int idx = q * 324 + ofs;
        int r = idx / 36, r2 = idx - r * 36;
        const float* pa = si + r * GST;
        const float* pb = si + r2 * GST;
        float a2 = acc[t];
#pragma unroll 8
        for (int e = 0; e < 256; e += 4) {
          float4 x = *(const float4*)(pa + e);
          float4 y = *(const float4*)(pb + e);
          a2 = fmaf(x.x, y.x, a2);
          a2 = fmaf(x.y, y.y, a2);
          a2 = fmaf(x.z, y.z, a2);
          a2 = fmaf(x.w, y.w, a2);
        }
        acc[t] = a2;
      }
    }
  }
#pragma unroll
  for (int t = 0; t < 2; ++t) {
    int ofs = t * 256 + (int)threadIdx.x;
    if (ofs < 324) G[(size_t)i * 1296 + q * 324 + ofs] = acc[t];
  }
}

// Main fused kernel. Block = (caption c, image-group of 4). Wave w handles
// image i = ig*4+w: S (64 tokens x 48-padded regions) via MFMA bf16, then
// per-token softmax(lam*S) over 36 regions, dot = p.S, nb^2 = p^T G p.
__global__ __launch_bounds__(256) void k_main(
    const unsigned short* __restrict__ capb,
    const unsigned short* __restrict__ imgb, const float* __restrict__ G,
    const int* __restrict__ lens, float* __restrict__ out) {
  __shared__ float S[4][64][49];
  int tid = threadIdx.x;
  int w = tid >> 6, lane = tid & 63;
  int c = blockIdx.x >> 4;
  int i = (blockIdx.x & 15) * 4 + w;
  int rq = lane & 15;  // row-in-tile for A, col-in-tile for B/D
  int kg = lane >> 4;  // k-group (0..3): k = kg*8 + j

  f32x4 acc[4][3];
#pragma unroll
  for (int m = 0; m < 4; ++m)
#pragma unroll
    for (int n = 0; n < 3; ++n) acc[m][n] = 0.f;

  const unsigned short* Ab = capb + ((size_t)c * LTOK + rq) * EDIM + kg * 8;
  const unsigned short* Bb = imgb + (size_t)i * RREG * EDIM + kg * 8;
  bf16x8 zerov = {};

#pragma unroll 2
  for (int kk = 0; kk < 16; ++kk) {
    int e = kk * 32;
    bf16x8 a0 = *(const bf16x8*)(Ab + 0 * 16 * EDIM + e);
    bf16x8 a1 = *(const bf16x8*)(Ab + 1 * 16 * EDIM + e);
    bf16x8 a2 = *(const bf16x8*)(Ab + 2 * 16 * EDIM + e);
    bf16x8 a3 = *(const bf16x8*)(Ab + 3 * 16 * EDIM + e);
    bf16x8 b0 = *(const bf16x8*)(Bb + (0 * 16 + rq) * EDIM + e);
    bf16x8 b1 = *(const bf16x8*)(Bb + (16 + rq) * EDIM + e);
    bf16x8 b2 = zerov;
    if (rq < 4) b2 = *(const bf16x8*)(Bb + (32 + rq) * EDIM + e);

    acc[0][0] = __builtin_amdgcn_mfma_f32_16x16x32_bf16(a0, b0, acc[0][0], 0, 0, 0);
    acc[0][1] = __builtin_amdgcn_mfma_f32_16x16x32_bf16(a0, b1, acc[0][1], 0, 0, 0);
    acc[0][2] = __builtin_amdgcn_mfma_f32_16x16x32_bf16(a0, b2, acc[0][2], 0, 0, 0);
    acc[1][0] = __builtin_amdgcn_mfma_f32_16x16x32_bf16(a1, b0, acc[1][0], 0, 0, 0);
    acc[1][1] = __builtin_amdgcn_mfma_f32_16x16x32_bf16(a1, b1, acc[1][1], 0, 0, 0);
    acc[1][2] = __builtin_amdgcn_mfma_f32_16x16x32_bf16(a1, b2, acc[1][2], 0, 0, 0);
    acc[2][0] = __builtin_amdgcn_mfma_f32_16x16x32_bf16(a2, b0, acc[2][0], 0, 0, 0);
    acc[2][1] = __builtin_amdgcn_mfma_f32_16x16x32_bf16(a2, b1, acc[2][1], 0, 0, 0);
    acc[2][2] = __builtin_amdgcn_mfma_f32_16x16x32_bf16(a2, b2, acc[2][2], 0, 0, 0);
    acc[3][0] = __builtin_amdgcn_mfma_f32_16x16x32_bf16(a3, b0, acc[3][0], 0, 0, 0);
    acc[3][1] = __builtin_amdgcn_mfma_f32_16x16x32_bf16(a3, b1, acc[3][1], 0, 0, 0);
    acc[3][2] = __builtin_amdgcn_mfma_f32_16x16x32_bf16(a3, b2, acc[3][2], 0, 0, 0);
  }

  // D layout: col = lane&15, row = (lane>>4)*4 + j
#pragma unroll
  for (int m = 0; m < 4; ++m)
#pragma unroll
    for (int n = 0; n < 3; ++n)
#pragma unroll
      for (int j = 0; j < 4; ++j)
        S[w][m * 16 + kg * 4 + j][n * 16 + rq] = acc[m][n][j];
  __syncthreads();

  // Epilogue: thread = (image w, token l = lane)
  float s[36], p[36];
#pragma unroll
  for (int r = 0; r < 36; ++r) s[r] = S[w][lane][r];
  float mx = s[0];
#pragma unroll
  for (int r = 1; r < 36; ++r) mx = fmaxf(mx, s[r]);
  float sum = 0.f, dotp = 0.f;
#pragma unroll
  for (int r = 0; r < 36; ++r) {
    p[r] = __expf(LAM * (s[r] - mx));
    sum += p[r];
    dotp = fmaf(p[r], s[r], dotp);
  }
  // nb^2 * sum^2 = p^T G p, with wave-uniform G pointer (scalar loads)
  int iu = __builtin_amdgcn_readfirstlane(i);
  const float* Gi = G + (size_t)iu * 1296;
  float q2 = 0.f;
#pragma unroll
  for (int r2 = 0; r2 < 36; ++r2) {
    float g = 0.f;
#pragma unroll
    for (int r = 0; r < 36; ++r) g = fmaf(Gi[r2 * 36 + r], p[r], g);
    q2 = fmaf(g, p[r2], q2);
  }
  float inv = 1.0f / sum;
  float dn = dotp * inv;
  float nb = sqrtf(fmaxf(q2, 0.f)) * inv;
  float rcos = dn / fmaxf(nb, 1e-8f);
  float val = (lane < lens[c]) ? rcos : 0.f;
#pragma unroll
  for (int off = 1; off < 64; off <<= 1) val += __shfl_xor(val, off);
  if (lane == 0) out[c * 64 + i] = val * (1.0f / 64.0f);
}

extern "C" void kernel_launch(void* const* d_in, const int* in_sizes, int n_in,
                              void* d_out, int out_size, void* d_ws,
                              size_t ws_size, hipStream_t stream) {
  const float* images = (const float*)d_in[0];    // (64,36,512) f32
  const float* captions = (const float*)d_in[1];  // (64,64,512) f32
  const int* lens = (const int*)d_in[2];          // (64,)
  float* out = (float*)d_out;                     // (64,64) f32

  char* ws = (char*)d_ws;
  unsigned short* capb = (unsigned short*)ws;               // 4096*512*2
  unsigned short* imgb = (unsigned short*)(ws + 4194304);   // 2304*512*2
  float* imgn = (float*)(ws + 4194304 + 2359296);           // 2304*512*4
  float* G = (float*)(ws + 4194304 + 2359296 + 4718592);    // 64*1296*4

  k_norm<<<1024, 256, 0, stream>>>(captions, capb, nullptr, NCAP * LTOK);
  k_norm<<<576, 256, 0, stream>>>(images, imgb, imgn, NIMG * RREG);
  k_gram<<<256, 256, 0, stream>>>(imgn, G);
  k_main<<<1024, 256, 0, stream>>>(capb, imgb, G, lens, out);
}

// Round 2
// 59.684 us; speedup vs baseline: 1.9354x; 1.9354x over previous
//
#include <hip/hip_runtime.h>
#include <stdint.h>

// Sizes (fixed by the problem)
#define NCAP 64
#define NIMG 64
#define LTOK 64
#define RREG 36
#define EDIM 512
#define LAM 9.0f

typedef __attribute__((ext_vector_type(8))) short bf16x8;
typedef __attribute__((ext_vector_type(4))) float f32x4;
typedef __attribute__((ext_vector_type(8))) unsigned short u16x8;

typedef const __attribute__((address_space(1))) void* gas1_t;
typedef __attribute__((address_space(3))) void* las3_t;

__device__ __forceinline__ void gl16(const void* g, void* l) {
  // stages 16B per lane: LDS dest = l + lane*16 (wave-uniform base), global
  // src = per-lane address g.
  __builtin_amdgcn_global_load_lds((gas1_t)g, (las3_t)l, 16, 0, 0);
}

__device__ __forceinline__ unsigned short f2bf(float f) {
  unsigned int u = __float_as_uint(f);
  u += 0x7FFFu + ((u >> 16) & 1u);  // RNE
  return (unsigned short)(u >> 16);
}

// Fused L2-normalize for captions (rows 0..4095) and images (rows 4096..6399).
// One wave per row of 512 f32. Captions -> bf16; images -> bf16 + f32.
__global__ __launch_bounds__(256) void k_norm(const float* __restrict__ cap,
                                              const float* __restrict__ img,
                                              unsigned short* __restrict__ capb,
                                              unsigned short* __restrict__ imgb,
                                              float* __restrict__ imgn) {
  int w = threadIdx.x >> 6, lane = threadIdx.x & 63;
  int v = blockIdx.x * 4 + w;
  bool isimg = v >= NCAP * LTOK;
  int vi = isimg ? v - NCAP * LTOK : v;
  const float* p = (isimg ? img : cap) + (size_t)vi * EDIM + lane * 8;
  float4 a = *(const float4*)p;
  float4 b = *(const float4*)(p + 4);
  float ss = a.x * a.x + a.y * a.y + a.z * a.z + a.w * a.w +
             b.x * b.x + b.y * b.y + b.z * b.z + b.w * b.w;
#pragma unroll
  for (int off = 1; off < 64; off <<= 1) ss += __shfl_xor(ss, off);
  float sc = 1.0f / fmaxf(sqrtf(ss), 1e-12f);
  float f0 = a.x * sc, f1 = a.y * sc, f2 = a.z * sc, f3 = a.w * sc;
  float f4 = b.x * sc, f5 = b.y * sc, f6 = b.z * sc, f7 = b.w * sc;
  u16x8 o = {f2bf(f0), f2bf(f1), f2bf(f2), f2bf(f3),
             f2bf(f4), f2bf(f5), f2bf(f6), f2bf(f7)};
  if (isimg) {
    *(u16x8*)(imgb + (size_t)vi * EDIM + lane * 8) = o;
    float* q = imgn + (size_t)vi * EDIM + lane * 8;
    *(float4*)q = make_float4(f0, f1, f2, f3);
    *(float4*)(q + 4) = make_float4(f4, f5, f6, f7);
  } else {
    *(u16x8*)(capb + (size_t)vi * EDIM + lane * 8) = o;
  }
}

// Per-image Gram matrix G2[i] = img_n[i] @ img_n[i]^T (36x36, fp32), with
// OFF-DIAGONAL ENTRIES PRE-DOUBLED (for the triangular quadratic form in
// k_main). 4 blocks per image.
#define GST 260
__global__ __launch_bounds__(256) void k_gram(const float* __restrict__ imgn,
                                              float* __restrict__ G) {
  __shared__ float si[RREG * GST];
  int i = blockIdx.x >> 2, q = blockIdx.x & 3;
  const float* base = imgn + (size_t)i * RREG * EDIM;
  float acc[2] = {0.f, 0.f};
  for (int pass = 0; pass < 2; ++pass) {
    __syncthreads();
    for (int t = threadIdx.x; t < RREG * 64; t += 256) {
      int row = t >> 6, e4 = t & 63;
      *(float4*)(si + row * GST + e4 * 4) =
          *(const float4*)(base + row * EDIM + pass * 256 + e4 * 4);
    }
    __syncthreads();
#pragma unroll
    for (int t = 0; t < 2; ++t) {
      int ofs = t * 256 + (int)threadIdx.x;
      if (ofs < 324) {
        int idx = q * 324 + ofs;
        int r = idx / 36, r2 = idx - r * 36;
        const float* pa = si + r * GST;
        const float* pb = si + r2 * GST;
        float a2 = acc[t];
#pragma unroll 8
        for (int e = 0; e < 256; e += 4) {
          float4 x = *(const float4*)(pa + e);
          float4 y = *(const float4*)(pb + e);
          a2 = fmaf(x.x, y.x, a2);
          a2 = fmaf(x.y, y.y, a2);
          a2 = fmaf(x.z, y.z, a2);
          a2 = fmaf(x.w, y.w, a2);
        }
        acc[t] = a2;
      }
    }
  }
#pragma unroll
  for (int t = 0; t < 2; ++t) {
    int ofs = t * 256 + (int)threadIdx.x;
    if (ofs < 324) {
      int idx = q * 324 + ofs;
      int r = idx / 36, r2 = idx - r * 36;
      float v = acc[t];
      G[(size_t)i * 1296 + idx] = (r == r2) ? v : 2.0f * v;
    }
  }
}

// ---------------- main fused kernel ----------------
// Block = (caption c, image-group of 4). Wave w -> image i = i0+w.
// K-loop (8 chunks of 64 cols): global_load_lds-staged, XOR-swizzled LDS,
// double-buffered. Then S -> LDS (overlaid on stage bufs), per-token softmax
// + dot + triangular Gram quadratic form.
#define STAGE_BYTES 26624   // cap 64x64 bf16 (8192) + img 144x64 bf16 (18432)
#define LDS_BYTES 53248     // 2 stage bufs == S[4][64][52] f32

__device__ __forceinline__ void stage_chunk(const unsigned short* capb,
                                            const unsigned short* imgb,
                                            char* buf, int c, int i0, int k,
                                            int w, int jr, int jc) {
  // 26 wave-instructions per chunk (8 cap + 18 img), wave w does t%4==w.
  // Each stages 8 rows x 128B; global source pre-swizzled: sub = jc ^ (row&7).
#pragma unroll
  for (int tt = 0; tt < 7; ++tt) {
    int t = w + tt * 4;
    if (t < 26) {
      int row = ((t < 8 ? t : t - 8) << 3) + jr;
      const unsigned short* src =
          (t < 8) ? capb + (size_t)(c * 64 + row) * EDIM
                  : imgb + (size_t)(i0 * RREG + row) * EDIM;
      int sub = jc ^ (row & 7);
      gl16(src + k * 64 + sub * 8, buf + t * 1024);
    }
  }
}

__device__ __forceinline__ void compute_chunk(const char* buf, int w, int rq,
                                              int kg, f32x4 (&acc)[4][3]) {
  int ha = rq & 7;
  int hb = (w * 4 + rq) & 7;          // (w*36 + {0,16} + rq) & 7
  int rb2 = w * RREG + 32 + (rq & 3); // clamp: lanes rq>=4 read dup rows
  int hb2 = rb2 & 7;                  // (their outputs land in unread S cols)
  const char* ib = buf + 8192;
#pragma unroll
  for (int kk = 0; kk < 2; ++kk) {
    int sg = kk * 4 + kg;
    int oa = (sg ^ ha) << 4;
    int ob = (sg ^ hb) << 4;
    bf16x8 a0 = *(const bf16x8*)(buf + (rq)*128 + oa);
    bf16x8 a1 = *(const bf16x8*)(buf + (16 + rq) * 128 + oa);
    bf16x8 a2 = *(const bf16x8*)(buf + (32 + rq) * 128 + oa);
    bf16x8 a3 = *(const bf16x8*)(buf + (48 + rq) * 128 + oa);
    bf16x8 b0 = *(const bf16x8*)(ib + (w * RREG + rq) * 128 + ob);
    bf16x8 b1 = *(const bf16x8*)(ib + (w * RREG + 16 + rq) * 128 + ob);
    bf16x8 b2 = *(const bf16x8*)(ib + rb2 * 128 + ((sg ^ hb2) << 4));

    acc[0][0] = __builtin_amdgcn_mfma_f32_16x16x32_bf16(a0, b0, acc[0][0], 0, 0, 0);
    acc[0][1] = __builtin_amdgcn_mfma_f32_16x16x32_bf16(a0, b1, acc[0][1], 0, 0, 0);
    acc[0][2] = __builtin_amdgcn_mfma_f32_16x16x32_bf16(a0, b2, acc[0][2], 0, 0, 0);
    acc[1][0] = __builtin_amdgcn_mfma_f32_16x16x32_bf16(a1, b0, acc[1][0], 0, 0, 0);
    acc[1][1] = __builtin_amdgcn_mfma_f32_16x16x32_bf16(a1, b1, acc[1][1], 0, 0, 0);
    acc[1][2] = __builtin_amdgcn_mfma_f32_16x16x32_bf16(a1, b2, acc[1][2], 0, 0, 0);
    acc[2][0] = __builtin_amdgcn_mfma_f32_16x16x32_bf16(a2, b0, acc[2][0], 0, 0, 0);
    acc[2][1] = __builtin_amdgcn_mfma_f32_16x16x32_bf16(a2, b1, acc[2][1], 0, 0, 0);
    acc[2][2] = __builtin_amdgcn_mfma_f32_16x16x32_bf16(a2, b2, acc[2][2], 0, 0, 0);
    acc[3][0] = __builtin_amdgcn_mfma_f32_16x16x32_bf16(a3, b0, acc[3][0], 0, 0, 0);
    acc[3][1] = __builtin_amdgcn_mfma_f32_16x16x32_bf16(a3, b1, acc[3][1], 0, 0, 0);
    acc[3][2] = __builtin_amdgcn_mfma_f32_16x16x32_bf16(a3, b2, acc[3][2], 0, 0, 0);
  }
}

__global__ __launch_bounds__(256, 3) void k_main(
    const unsigned short* __restrict__ capb,
    const unsigned short* __restrict__ imgb, const float* __restrict__ G2,
    const int* __restrict__ lens, float* __restrict__ out) {
  __shared__ __align__(16) char lds[LDS_BYTES];
  int tid = threadIdx.x;
  int w = tid >> 6, lane = tid & 63;
  int bid = blockIdx.x;
  int b = (bid & 7) * 128 + (bid >> 3);  // XCD-aware swizzle (1024 % 8 == 0)
  int c = b >> 4;
  int i0 = (b & 15) * 4;
  int i = i0 + w;
  int rq = lane & 15, kg = lane >> 4;
  int jr = lane >> 3, jc = lane & 7;

  f32x4 acc[4][3];
#pragma unroll
  for (int m = 0; m < 4; ++m)
#pragma unroll
    for (int n = 0; n < 3; ++n) acc[m][n] = 0.f;

  stage_chunk(capb, imgb, lds, c, i0, 0, w, jr, jc);
  __syncthreads();
  for (int k = 0; k < 8; ++k) {
    if (k < 7)
      stage_chunk(capb, imgb, lds + ((k + 1) & 1) * STAGE_BYTES, c, i0, k + 1,
                  w, jr, jc);
    compute_chunk(lds + (k & 1) * STAGE_BYTES, w, rq, kg, acc);
    __syncthreads();
  }

  // S (overlaid on stage bufs): [4][64][52] f32. D layout: col = lane&15,
  // row = (lane>>4)*4 + j.
  float* Sf = (float*)lds;
#pragma unroll
  for (int m = 0; m < 4; ++m)
#pragma unroll
    for (int n = 0; n < 3; ++n)
#pragma unroll
      for (int j = 0; j < 4; ++j)
        Sf[(size_t)(w * 64 + m * 16 + kg * 4 + j) * 52 + n * 16 + rq] =
            acc[m][n][j];
  __syncthreads();

  // Epilogue: thread = (image w, token l = lane)
  const float* Srow = (const float*)lds + (size_t)(w * 64 + lane) * 52;
  float s[36];
#pragma unroll
  for (int r4 = 0; r4 < 9; ++r4) {
    float4 x = *(const float4*)(Srow + r4 * 4);
    s[r4 * 4 + 0] = x.x;
    s[r4 * 4 + 1] = x.y;
    s[r4 * 4 + 2] = x.z;
    s[r4 * 4 + 3] = x.w;
  }
  float mx = s[0];
#pragma unroll
  for (int r = 1; r < 36; ++r) mx = fmaxf(mx, s[r]);
  float p[36];
  float sum = 0.f, dotp = 0.f;
#pragma unroll
  for (int r = 0; r < 36; ++r) {
    p[r] = __expf(LAM * (s[r] - mx));
    sum += p[r];
    dotp = fmaf(p[r], s[r], dotp);
  }
  // q2 = p^T G p via triangular loop (G2 has off-diag pre-doubled)
  int iu = __builtin_amdgcn_readfirstlane(i);
  const float* Gi = G2 + (size_t)iu * 1296;
  float q2 = 0.f;
#pragma unroll
  for (int r2 = 0; r2 < 36; ++r2) {
    float t = 0.f;
#pragma unroll
    for (int r = 0; r <= r2; ++r) t = fmaf(Gi[r2 * 36 + r], p[r], t);
    q2 = fmaf(t, p[r2], q2);
  }
  float inv = 1.0f / sum;
  float dn = dotp * inv;
  float nb = sqrtf(fmaxf(q2, 0.f)) * inv;
  float rcos = dn / fmaxf(nb, 1e-8f);
  int len = lens[c];
  float val = (lane < len) ? rcos : 0.f;
#pragma unroll
  for (int off = 1; off < 64; off <<= 1) val += __shfl_xor(val, off);
  if (lane == 0) out[c * 64 + i] = val * (1.0f / 64.0f);
}

extern "C" void kernel_launch(void* const* d_in, const int* in_sizes, int n_in,
                              void* d_out, int out_size, void* d_ws,
                              size_t ws_size, hipStream_t stream) {
  const float* images = (const float*)d_in[0];    // (64,36,512) f32
  const float* captions = (const float*)d_in[1];  // (64,64,512) f32
  const int* lens = (const int*)d_in[2];          // (64,)
  float* out = (float*)d_out;                     // (64,64) f32

  char* ws = (char*)d_ws;
  unsigned short* capb = (unsigned short*)ws;               // 4096*512*2
  unsigned short* imgb = (unsigned short*)(ws + 4194304);   // 2304*512*2
  float* imgn = (float*)(ws + 4194304 + 2359296);           // 2304*512*4
  float* G = (float*)(ws + 4194304 + 2359296 + 4718592);    // 64*1296*4

  k_norm<<<1600, 256, 0, stream>>>(captions, images, capb, imgb, imgn);
  k_gram<<<256, 256, 0, stream>>>(imgn, G);
  k_main<<<1024, 256, 0, stream>>>(capb, imgb, G, lens, out);
}

// Round 3
// 54.968 us; speedup vs baseline: 2.1015x; 1.0858x over previous
//
#include <hip/hip_runtime.h>
#include <stdint.h>

// Sizes (fixed by the problem)
#define NCAP 64
#define NIMG 64
#define LTOK 64
#define RREG 36
#define EDIM 512
#define LAM 9.0f

typedef __attribute__((ext_vector_type(8))) short bf16x8;
typedef __attribute__((ext_vector_type(4))) float f32x4;
typedef __attribute__((ext_vector_type(8))) unsigned short u16x8;

__device__ __forceinline__ unsigned short f2bf(float f) {
  unsigned int u = __float_as_uint(f);
  u += 0x7FFFu + ((u >> 16) & 1u);  // RNE
  return (unsigned short)(u >> 16);
}

// L2-normalize rows and scatter into MFMA-fragment layout.
//   capT: per caption c, fragment (m,kk) (m=0..3 row-tiles of 16, kk=0..15
//         k-steps of 32) is 1KB contiguous: lane (kg*16+rq) holds 16B.
//   imgT: per image i, 48 pseudo-rows (36 real + 12 zero), tiles n=0..2.
// Wave w handles one row; v < 4096 -> captions, else images (48 rows/img).
__global__ __launch_bounds__(256) void k_norm(const float* __restrict__ cap,
                                              const float* __restrict__ img,
                                              unsigned short* __restrict__ capT,
                                              unsigned short* __restrict__ imgT) {
  int w = threadIdx.x >> 6, lane = threadIdx.x & 63;
  int v = blockIdx.x * 4 + w;
  int kkw = lane >> 2, kgw = lane & 3;  // this lane's (kk, kg) in frag layout

  const float* p;
  unsigned short* dst;
  if (v < NCAP * LTOK) {
    int c = v >> 6, row = v & 63;
    int m = row >> 4, rqw = row & 15;
    p = cap + (size_t)v * EDIM + lane * 8;
    dst = capT + (size_t)c * 32768 +
          (size_t)(((m * 16 + kkw) * 64 + kgw * 16 + rqw) * 8);
  } else {
    int vi = v - NCAP * LTOK;
    int i = vi / 48;
    int r = vi - i * 48;
    int n = r >> 4, rqw = r & 15;
    dst = imgT + (size_t)i * 24576 +
          (size_t)(((n * 16 + kkw) * 64 + kgw * 16 + rqw) * 8);
    if (r >= RREG) {  // pad row of tile 2 -> zeros
      u16x8 z = {};
      *(u16x8*)dst = z;
      return;
    }
    p = img + ((size_t)i * RREG + r) * EDIM + lane * 8;
  }

  float4 a = *(const float4*)p;
  float4 b = *(const float4*)(p + 4);
  float ss = a.x * a.x + a.y * a.y + a.z * a.z + a.w * a.w +
             b.x * b.x + b.y * b.y + b.z * b.z + b.w * b.w;
#pragma unroll
  for (int off = 1; off < 64; off <<= 1) ss += __shfl_xor(ss, off);
  float sc = 1.0f / fmaxf(sqrtf(ss), 1e-12f);
  u16x8 o = {f2bf(a.x * sc), f2bf(a.y * sc), f2bf(a.z * sc), f2bf(a.w * sc),
             f2bf(b.x * sc), f2bf(b.y * sc), f2bf(b.z * sc), f2bf(b.w * sc)};
  *(u16x8*)dst = o;
}

// Per-image Gram matrix from RAW images, normalized internally:
// G2[i][r][r2] = dot(img_i_r, img_i_r2) * invn_r * invn_r2, off-diag doubled.
// 4 blocks per image, two 256-col passes staged in LDS.
#define GST 260
__global__ __launch_bounds__(256) void k_gram(const float* __restrict__ img,
                                              float* __restrict__ G) {
  __shared__ float si[RREG * GST];
  __shared__ float invn[RREG];
  int i = blockIdx.x >> 2, q = blockIdx.x & 3;
  int w = threadIdx.x >> 6, lane = threadIdx.x & 63;
  const float* base = img + (size_t)i * RREG * EDIM;
  float acc[2] = {0.f, 0.f};
  float ssr[9];
#pragma unroll
  for (int t = 0; t < 9; ++t) ssr[t] = 0.f;

  for (int pass = 0; pass < 2; ++pass) {
    __syncthreads();
    for (int t = threadIdx.x; t < RREG * 64; t += 256) {
      int row = t >> 6, e4 = t & 63;
      *(float4*)(si + row * GST + e4 * 4) =
          *(const float4*)(base + row * EDIM + pass * 256 + e4 * 4);
    }
    __syncthreads();
    // per-row sum-of-squares partials: wave w covers rows w, w+4, ...
#pragma unroll
    for (int t = 0; t < 9; ++t) {
      int row = w + t * 4;
      float4 x = *(const float4*)(si + row * GST + lane * 4);
      ssr[t] += x.x * x.x + x.y * x.y + x.z * x.z + x.w * x.w;
    }
    // dot products (raw)
#pragma unroll
    for (int t = 0; t < 2; ++t) {
      int ofs = t * 256 + (int)threadIdx.x;
      if (ofs < 324) {
        int idx = q * 324 + ofs;
        int r = idx / 36, r2 = idx - r * 36;
        const float* pa = si + r * GST;
        const float* pb = si + r2 * GST;
        float a2 = acc[t];
#pragma unroll 8
        for (int e = 0; e < 256; e += 4) {
          float4 x = *(const float4*)(pa + e);
          float4 y = *(const float4*)(pb + e);
          a2 = fmaf(x.x, y.x, a2);
          a2 = fmaf(x.y, y.y, a2);
          a2 = fmaf(x.z, y.z, a2);
          a2 = fmaf(x.w, y.w, a2);
        }
        acc[t] = a2;
      }
    }
  }
  // finish row norms
#pragma unroll
  for (int t = 0; t < 9; ++t) {
    float ss = ssr[t];
#pragma unroll
    for (int off = 1; off < 64; off <<= 1) ss += __shfl_xor(ss, off);
    if (lane == 0) invn[w + t * 4] = 1.0f / fmaxf(sqrtf(ss), 1e-12f);
  }
  __syncthreads();
#pragma unroll
  for (int t = 0; t < 2; ++t) {
    int ofs = t * 256 + (int)threadIdx.x;
    if (ofs < 324) {
      int idx = q * 324 + ofs;
      int r = idx / 36, r2 = idx - r * 36;
      float vv = acc[t] * invn[r] * invn[r2];
      G[(size_t)i * 1296 + idx] = (r == r2) ? vv : 2.0f * vv;
    }
  }
}

// ---------------- main fused kernel ----------------
// Block = (caption c, image-group of 4); wave w -> image i = i0+w.
// Barrier-free K-loop: MFMA fragments loaded directly from pre-transposed
// global layout (every load = 64 lanes x 16B contiguous). LDS only for the
// S exchange before the per-token epilogue.
#define SSTR 38  // f32 words per S row (>=36, even for float2, bank-friendly)

__global__ __launch_bounds__(256, 3) void k_main(
    const unsigned short* __restrict__ capT,
    const unsigned short* __restrict__ imgT, const float* __restrict__ G2,
    const int* __restrict__ lens, float* __restrict__ out) {
  __shared__ __align__(16) float Sf[4 * 64 * SSTR];  // 38912 B
  int tid = threadIdx.x;
  int w = tid >> 6, lane = tid & 63;
  int bid = blockIdx.x;
  int b = (bid & 7) * 128 + (bid >> 3);  // XCD-aware swizzle (1024 % 8 == 0)
  int c = b >> 4;
  int i = (b & 15) * 4 + w;
  int rq = lane & 15, kg = lane >> 4;

  const unsigned short* Ab = capT + (size_t)c * 32768 + lane * 8;
  const unsigned short* Bb = imgT + (size_t)i * 24576 + lane * 8;

  f32x4 acc[4][3];
#pragma unroll
  for (int m = 0; m < 4; ++m)
#pragma unroll
    for (int n = 0; n < 3; ++n) acc[m][n] = 0.f;

#pragma unroll
  for (int kk = 0; kk < 16; ++kk) {
    bf16x8 a0 = *(const bf16x8*)(Ab + (kk + 0) * 512);
    bf16x8 a1 = *(const bf16x8*)(Ab + (kk + 16) * 512);
    bf16x8 a2 = *(const bf16x8*)(Ab + (kk + 32) * 512);
    bf16x8 a3 = *(const bf16x8*)(Ab + (kk + 48) * 512);
    bf16x8 b0 = *(const bf16x8*)(Bb + (kk + 0) * 512);
    bf16x8 b1 = *(const bf16x8*)(Bb + (kk + 16) * 512);
    bf16x8 b2 = *(const bf16x8*)(Bb + (kk + 32) * 512);

    acc[0][0] = __builtin_amdgcn_mfma_f32_16x16x32_bf16(a0, b0, acc[0][0], 0, 0, 0);
    acc[0][1] = __builtin_amdgcn_mfma_f32_16x16x32_bf16(a0, b1, acc[0][1], 0, 0, 0);
    acc[0][2] = __builtin_amdgcn_mfma_f32_16x16x32_bf16(a0, b2, acc[0][2], 0, 0, 0);
    acc[1][0] = __builtin_amdgcn_mfma_f32_16x16x32_bf16(a1, b0, acc[1][0], 0, 0, 0);
    acc[1][1] = __builtin_amdgcn_mfma_f32_16x16x32_bf16(a1, b1, acc[1][1], 0, 0, 0);
    acc[1][2] = __builtin_amdgcn_mfma_f32_16x16x32_bf16(a1, b2, acc[1][2], 0, 0, 0);
    acc[2][0] = __builtin_amdgcn_mfma_f32_16x16x32_bf16(a2, b0, acc[2][0], 0, 0, 0);
    acc[2][1] = __builtin_amdgcn_mfma_f32_16x16x32_bf16(a2, b1, acc[2][1], 0, 0, 0);
    acc[2][2] = __builtin_amdgcn_mfma_f32_16x16x32_bf16(a2, b2, acc[2][2], 0, 0, 0);
    acc[3][0] = __builtin_amdgcn_mfma_f32_16x16x32_bf16(a3, b0, acc[3][0], 0, 0, 0);
    acc[3][1] = __builtin_amdgcn_mfma_f32_16x16x32_bf16(a3, b1, acc[3][1], 0, 0, 0);
    acc[3][2] = __builtin_amdgcn_mfma_f32_16x16x32_bf16(a3, b2, acc[3][2], 0, 0, 0);
  }

  // S exchange. D layout: col = lane&15, row = (lane>>4)*4 + j.
  // Guard n==2 stores to cols 32..35 (pad cols 36..47 are zeros, unread).
#pragma unroll
  for (int m = 0; m < 4; ++m)
#pragma unroll
    for (int n = 0; n < 3; ++n)
#pragma unroll
      for (int j = 0; j < 4; ++j)
        if (n < 2 || rq < 4)
          Sf[(w * 64 + m * 16 + kg * 4 + j) * SSTR + n * 16 + rq] =
              acc[m][n][j];
  __syncthreads();

  // Epilogue: thread = (image w, token l = lane)
  const float* Srow = Sf + (size_t)(w * 64 + lane) * SSTR;
  float s[36];
#pragma unroll
  for (int r2 = 0; r2 < 18; ++r2) {
    float2 x = *(const float2*)(Srow + r2 * 2);
    s[r2 * 2 + 0] = x.x;
    s[r2 * 2 + 1] = x.y;
  }
  float mx = s[0];
#pragma unroll
  for (int r = 1; r < 36; ++r) mx = fmaxf(mx, s[r]);
  float p[36];
  float sum = 0.f, dotp = 0.f;
#pragma unroll
  for (int r = 0; r < 36; ++r) {
    p[r] = __expf(LAM * (s[r] - mx));
    sum += p[r];
    dotp = fmaf(p[r], s[r], dotp);
  }
  // q2 = p^T G p via triangular loop (G2 has off-diag pre-doubled)
  int iu = __builtin_amdgcn_readfirstlane(i);
  const float* Gi = G2 + (size_t)iu * 1296;
  float q2 = 0.f;
#pragma unroll
  for (int r2 = 0; r2 < 36; ++r2) {
    float t = 0.f;
#pragma unroll
    for (int r = 0; r <= r2; ++r) t = fmaf(Gi[r2 * 36 + r], p[r], t);
    q2 = fmaf(t, p[r2], q2);
  }
  float inv = 1.0f / sum;
  float dn = dotp * inv;
  float nb = sqrtf(fmaxf(q2, 0.f)) * inv;
  float rcos = dn / fmaxf(nb, 1e-8f);
  int len = lens[c];
  float val = (lane < len) ? rcos : 0.f;
#pragma unroll
  for (int off = 1; off < 64; off <<= 1) val += __shfl_xor(val, off);
  if (lane == 0) out[c * 64 + i] = val * (1.0f / 64.0f);
}

extern "C" void kernel_launch(void* const* d_in, const int* in_sizes, int n_in,
                              void* d_out, int out_size, void* d_ws,
                              size_t ws_size, hipStream_t stream) {
  const float* images = (const float*)d_in[0];    // (64,36,512) f32
  const float* captions = (const float*)d_in[1];  // (64,64,512) f32
  const int* lens = (const int*)d_in[2];          // (64,)
  float* out = (float*)d_out;                     // (64,64) f32

  char* ws = (char*)d_ws;
  unsigned short* capT = (unsigned short*)ws;              // 4096*512*2 = 4 MB
  unsigned short* imgT = (unsigned short*)(ws + 4194304);  // 64*24576*2 = 3 MB
  float* G = (float*)(ws + 4194304 + 3145728);             // 64*1296*4

  // 4096 caption rows + 64*48 image pseudo-rows = 7168 rows / 4 waves
  k_norm<<<1792, 256, 0, stream>>>(captions, images, capT, imgT);
  k_gram<<<256, 256, 0, stream>>>(images, G);
  k_main<<<1024, 256, 0, stream>>>(capT, imgT, G, lens, out);
}

// Round 5
// 51.487 us; speedup vs baseline: 2.2435x; 1.0676x over previous
//
#include <hip/hip_runtime.h>
#include <stdint.h>

// Sizes (fixed by the problem)
#define NCAP 64
#define NIMG 64
#define LTOK 64
#define RREG 36
#define EDIM 512
#define LAM 9.0f
#define GST 260  // gram LDS row stride (floats)
#define SSTR 38  // S-exchange row stride (floats)

typedef __attribute__((ext_vector_type(8))) short bf16x8;
typedef __attribute__((ext_vector_type(4))) float f32x4;
typedef __attribute__((ext_vector_type(8))) unsigned short u16x8;

typedef const __attribute__((address_space(1))) void* gas1_t;
typedef __attribute__((address_space(3))) void* las3_t;

__device__ __forceinline__ void gl16(const void* g, void* l) {
  // stages 16B per lane: LDS dest = l + lane*16 (wave-uniform base), global
  // src = per-lane address g.
  __builtin_amdgcn_global_load_lds((gas1_t)g, (las3_t)l, 16, 0, 0);
}

__device__ __forceinline__ unsigned short f2bf(float f) {
  unsigned int u = __float_as_uint(f);
  u += 0x7FFFu + ((u >> 16) & 1u);  // RNE
  return (unsigned short)(u >> 16);
}

// Fused prep kernel, 2048 blocks:
//   blocks 0..1791: L2-normalize 7168 rows (4096 caption + 3072 image
//     pseudo-rows incl. zero pad) into MFMA fragment layout (1 row/wave).
//   blocks 1792..2047: Gram quadrants (4 blocks/image, 324 entries each),
//     normalized internally from raw f32 images, off-diag pre-doubled.
__global__ __launch_bounds__(256) void k_prep(const float* __restrict__ cap,
                                              const float* __restrict__ img,
                                              unsigned short* __restrict__ capT,
                                              unsigned short* __restrict__ imgT,
                                              float* __restrict__ G2) {
  __shared__ float si[RREG * GST + RREG];  // gram staging + invn
  int tid = threadIdx.x;
  int w = tid >> 6, lane = tid & 63;
  int bid = blockIdx.x;

  if (bid < 1792) {
    // ---- norm + fragment scatter ----
    int kkw = lane >> 2, kgw = lane & 3;  // lane's (kk, kg) in frag layout
    int v = bid * 4 + w;
    const float* p;
    unsigned short* dst;
    if (v < NCAP * LTOK) {
      int c = v >> 6, row = v & 63;
      int m = row >> 4, rqw = row & 15;
      p = cap + (size_t)v * EDIM + lane * 8;
      dst = capT + (size_t)c * 32768 +
            (size_t)(((m * 16 + kkw) * 64 + kgw * 16 + rqw) * 8);
    } else {
      int vi = v - NCAP * LTOK;
      int i = vi / 48;
      int r = vi - i * 48;
      int n = r >> 4, rqw = r & 15;
      dst = imgT + (size_t)i * 24576 +
            (size_t)(((n * 16 + kkw) * 64 + kgw * 16 + rqw) * 8);
      if (r >= RREG) {  // pad row of tile 2 -> zeros
        u16x8 z = {};
        *(u16x8*)dst = z;
        return;
      }
      p = img + ((size_t)i * RREG + r) * EDIM + lane * 8;
    }
    float4 a = *(const float4*)p;
    float4 b = *(const float4*)(p + 4);
    float ss = a.x * a.x + a.y * a.y + a.z * a.z + a.w * a.w +
               b.x * b.x + b.y * b.y + b.z * b.z + b.w * b.w;
#pragma unroll
    for (int off = 1; off < 64; off <<= 1) ss += __shfl_xor(ss, off);
    float sc = 1.0f / fmaxf(sqrtf(ss), 1e-12f);
    u16x8 o = {f2bf(a.x * sc), f2bf(a.y * sc), f2bf(a.z * sc), f2bf(a.w * sc),
               f2bf(b.x * sc), f2bf(b.y * sc), f2bf(b.z * sc), f2bf(b.w * sc)};
    *(u16x8*)dst = o;
    return;
  }

  // ---- gram ----
  float* invn = si + RREG * GST;
  int qb = bid - 1792;
  int i = qb >> 2, q = qb & 3;
  const float* base = img + (size_t)i * RREG * EDIM;
  float acc[2] = {0.f, 0.f};
  float ssr[9];
#pragma unroll
  for (int t = 0; t < 9; ++t) ssr[t] = 0.f;

  for (int pass = 0; pass < 2; ++pass) {
    __syncthreads();
    for (int t = tid; t < RREG * 64; t += 256) {
      int row = t >> 6, e4 = t & 63;
      *(float4*)(si + row * GST + e4 * 4) =
          *(const float4*)(base + row * EDIM + pass * 256 + e4 * 4);
    }
    __syncthreads();
    // per-row sum-of-squares partials: wave w covers rows w, w+4, ...
#pragma unroll
    for (int t = 0; t < 9; ++t) {
      int row = w + t * 4;
      float4 x = *(const float4*)(si + row * GST + lane * 4);
      ssr[t] += x.x * x.x + x.y * x.y + x.z * x.z + x.w * x.w;
    }
#pragma unroll
    for (int t = 0; t < 2; ++t) {
      int ofs = t * 256 + tid;
      if (ofs < 324) {
        int idx = q * 324 + ofs;
        int r = idx / 36, r2 = idx - r * 36;
        const float* pa = si + r * GST;
        const float* pb = si + r2 * GST;
        float a2 = acc[t];
#pragma unroll 8
        for (int e = 0; e < 256; e += 4) {
          float4 x = *(const float4*)(pa + e);
          float4 y = *(const float4*)(pb + e);
          a2 = fmaf(x.x, y.x, a2);
          a2 = fmaf(x.y, y.y, a2);
          a2 = fmaf(x.z, y.z, a2);
          a2 = fmaf(x.w, y.w, a2);
        }
        acc[t] = a2;
      }
    }
  }
  // finish row norms
#pragma unroll
  for (int t = 0; t < 9; ++t) {
    float ss = ssr[t];
#pragma unroll
    for (int off = 1; off < 64; off <<= 1) ss += __shfl_xor(ss, off);
    if (lane == 0) invn[w + t * 4] = 1.0f / fmaxf(sqrtf(ss), 1e-12f);
  }
  __syncthreads();
#pragma unroll
  for (int t = 0; t < 2; ++t) {
    int ofs = t * 256 + tid;
    if (ofs < 324) {
      int idx = q * 324 + ofs;
      int r = idx / 36, r2 = idx - r * 36;
      float vv = acc[t] * invn[r] * invn[r2];
      G2[(size_t)i * 1296 + idx] = (r == r2) ? vv : 2.0f * vv;
    }
  }
}

// ---------------- main fused kernel ----------------
// Block = (caption c, image-group of 4); wave w -> image i0+w.
// A (capT[c], 64KB) staged ONCE per block into LDS in two 32KB K-halves
// via global_load_lds (removes the 4x per-wave A redundancy of round 3);
// B fragments stay per-wave direct global loads (L2-resident). A-half
// region is overlaid by the S-exchange buffer after the GEMM.
__global__ __launch_bounds__(256, 4) void k_main(
    const unsigned short* __restrict__ capT,
    const unsigned short* __restrict__ imgT, const float* __restrict__ G2,
    const int* __restrict__ lens, float* __restrict__ out) {
  __shared__ __align__(16) float lds[4 * 64 * SSTR];  // 38912 B
  int tid = threadIdx.x;
  int w = tid >> 6, lane = tid & 63;
  int bid = blockIdx.x;
  int b = (bid & 7) * 128 + (bid >> 3);  // XCD-aware swizzle (1024 % 8 == 0)
  int c = b >> 4;
  int i = (b & 15) * 4 + w;
  int rq = lane & 15, kg = lane >> 4;

  const unsigned short* Acap = capT + (size_t)c * 32768;
  const unsigned short* Bb = imgT + (size_t)i * 24576 + lane * 8;
  char* ldsb = (char*)lds;

  f32x4 acc[4][3];
#pragma unroll
  for (int m = 0; m < 4; ++m)
#pragma unroll
    for (int n = 0; n < 3; ++n) acc[m][n] = 0.f;

  // Stage A-half h: wave w stages m-tile w's 8 frags. LDS frag id = m*8+kk,
  // global frag id = m*16 + h*8 + kk (capT layout [m][kk_global]).
#define STAGE_A(h)                                                         \
  {                                                                        \
    _Pragma("unroll") for (int j = 0; j < 8; ++j) {                        \
      gl16(Acap + (size_t)(w * 16 + (h)*8 + j) * 512 + lane * 8,           \
           ldsb + (w * 8 + j) * 1024);                                     \
    }                                                                      \
  }

  STAGE_A(0);
  __syncthreads();
#pragma unroll
  for (int h = 0; h < 2; ++h) {
#pragma unroll
    for (int kk = 0; kk < 8; ++kk) {
      bf16x8 a0 = *(const bf16x8*)(ldsb + (0 * 8 + kk) * 1024 + lane * 16);
      bf16x8 a1 = *(const bf16x8*)(ldsb + (1 * 8 + kk) * 1024 + lane * 16);
      bf16x8 a2 = *(const bf16x8*)(ldsb + (2 * 8 + kk) * 1024 + lane * 16);
      bf16x8 a3 = *(const bf16x8*)(ldsb + (3 * 8 + kk) * 1024 + lane * 16);
      int kgl = h * 8 + kk;
      bf16x8 b0 = *(const bf16x8*)(Bb + (0 * 16 + kgl) * 512);
      bf16x8 b1 = *(const bf16x8*)(Bb + (1 * 16 + kgl) * 512);
      bf16x8 b2 = *(const bf16x8*)(Bb + (2 * 16 + kgl) * 512);

      acc[0][0] = __builtin_amdgcn_mfma_f32_16x16x32_bf16(a0, b0, acc[0][0], 0, 0, 0);
      acc[0][1] = __builtin_amdgcn_mfma_f32_16x16x32_bf16(a0, b1, acc[0][1], 0, 0, 0);
      acc[0][2] = __builtin_amdgcn_mfma_f32_16x16x32_bf16(a0, b2, acc[0][2], 0, 0, 0);
      acc[1][0] = __builtin_amdgcn_mfma_f32_16x16x32_bf16(a1, b0, acc[1][0], 0, 0, 0);
      acc[1][1] = __builtin_amdgcn_mfma_f32_16x16x32_bf16(a1, b1, acc[1][1], 0, 0, 0);
      acc[1][2] = __builtin_amdgcn_mfma_f32_16x16x32_bf16(a1, b2, acc[1][2], 0, 0, 0);
      acc[2][0] = __builtin_amdgcn_mfma_f32_16x16x32_bf16(a2, b0, acc[2][0], 0, 0, 0);
      acc[2][1] = __builtin_amdgcn_mfma_f32_16x16x32_bf16(a2, b1, acc[2][1], 0, 0, 0);
      acc[2][2] = __builtin_amdgcn_mfma_f32_16x16x32_bf16(a2, b2, acc[2][2], 0, 0, 0);
      acc[3][0] = __builtin_amdgcn_mfma_f32_16x16x32_bf16(a3, b0, acc[3][0], 0, 0, 0);
      acc[3][1] = __builtin_amdgcn_mfma_f32_16x16x32_bf16(a3, b1, acc[3][1], 0, 0, 0);
      acc[3][2] = __builtin_amdgcn_mfma_f32_16x16x32_bf16(a3, b2, acc[3][2], 0, 0, 0);
    }
    if (h == 0) {
      __syncthreads();  // all waves done reading A-half0
      STAGE_A(1);
      __syncthreads();  // A-half1 staged (vmcnt drained by barrier)
    }
  }
  __syncthreads();  // all waves done reading A-half1 before S overwrite

  // S exchange. D layout: col = lane&15, row = (lane>>4)*4 + j.
  // Guard n==2 stores to cols 32..35 (pad cols 36..47 are zeros, unread).
#pragma unroll
  for (int m = 0; m < 4; ++m)
#pragma unroll
    for (int n = 0; n < 3; ++n)
#pragma unroll
      for (int j = 0; j < 4; ++j)
        if (n < 2 || rq < 4)
          lds[(w * 64 + m * 16 + kg * 4 + j) * SSTR + n * 16 + rq] =
              acc[m][n][j];
  __syncthreads();

  // Epilogue: thread = (image w, token l = lane)
  const float* Srow = lds + (size_t)(w * 64 + lane) * SSTR;
  float s[36];
#pragma unroll
  for (int r2 = 0; r2 < 18; ++r2) {
    float2 x = *(const float2*)(Srow + r2 * 2);
    s[r2 * 2 + 0] = x.x;
    s[r2 * 2 + 1] = x.y;
  }
  float mx = s[0];
#pragma unroll
  for (int r = 1; r < 36; ++r) mx = fmaxf(mx, s[r]);
  float p[36];
  float sum = 0.f, dotp = 0.f;
#pragma unroll
  for (int r = 0; r < 36; ++r) {
    p[r] = __expf(LAM * (s[r] - mx));
    sum += p[r];
    dotp = fmaf(p[r], s[r], dotp);
  }
  // q2 = p^T G p via triangular loop (G2 has off-diag pre-doubled)
  int iu = __builtin_amdgcn_readfirstlane(i);
  const float* Gi = G2 + (size_t)iu * 1296;
  float q2 = 0.f;
#pragma unroll
  for (int r2 = 0; r2 < 36; ++r2) {
    float t = 0.f;
#pragma unroll
    for (int r = 0; r <= r2; ++r) t = fmaf(Gi[r2 * 36 + r], p[r], t);
    q2 = fmaf(t, p[r2], q2);
  }
  float inv = 1.0f / sum;
  float dn = dotp * inv;
  float nb = sqrtf(fmaxf(q2, 0.f)) * inv;
  float rcos = dn / fmaxf(nb, 1e-8f);
  int len = lens[c];
  float val = (lane < len) ? rcos : 0.f;
#pragma unroll
  for (int off = 1; off < 64; off <<= 1) val += __shfl_xor(val, off);
  if (lane == 0) out[c * 64 + i] = val * (1.0f / 64.0f);
}

extern "C" void kernel_launch(void* const* d_in, const int* in_sizes, int n_in,
                              void* d_out, int out_size, void* d_ws,
                              size_t ws_size, hipStream_t stream) {
  const float* images = (const float*)d_in[0];    // (64,36,512) f32
  const float* captions = (const float*)d_in[1];  // (64,64,512) f32
  const int* lens = (const int*)d_in[2];          // (64,)
  float* out = (float*)d_out;                     // (64,64) f32

  char* ws = (char*)d_ws;
  unsigned short* capT = (unsigned short*)ws;              // 4096*512*2 = 4 MB
  unsigned short* imgT = (unsigned short*)(ws + 4194304);  // 64*24576*2 = 3 MB
  float* G = (float*)(ws + 4194304 + 3145728);             // 64*1296*4

  k_prep<<<2048, 256, 0, stream>>>(captions, images, capT, imgT, G);
  k_main<<<1024, 256, 0, stream>>>(capT, imgT, G, lens, out);
}

// Round 6
// 50.264 us; speedup vs baseline: 2.2982x; 1.0243x over previous
//
#include <hip/hip_runtime.h>
#include <stdint.h>

// Sizes (fixed by the problem)
#define NCAP 64
#define NIMG 64
#define LTOK 64
#define RREG 36
#define EDIM 512
#define LAM 9.0f
#define GST 260  // gram LDS row stride (floats)
#define SSTR 38  // S-exchange row stride (floats)

// imgT per-image layout (shorts): 32 full frags (n=0,1; 512 shorts each) at
// 0..16383, then 16 quarter-frags (n=2 rows 32..35; 128 shorts each) at
// 16384..18431. Per-image stride 18432 shorts = 36864 B.
#define IMGT_STRIDE 18432

typedef __attribute__((ext_vector_type(8))) short bf16x8;
typedef __attribute__((ext_vector_type(4))) float f32x4;
typedef __attribute__((ext_vector_type(8))) unsigned short u16x8;

typedef const __attribute__((address_space(1))) void* gas1_t;
typedef __attribute__((address_space(3))) void* las3_t;

__device__ __forceinline__ void gl16(const void* g, void* l) {
  __builtin_amdgcn_global_load_lds((gas1_t)g, (las3_t)l, 16, 0, 0);
}

__device__ __forceinline__ unsigned short f2bf(float f) {
  unsigned int u = __float_as_uint(f);
  u += 0x7FFFu + ((u >> 16) & 1u);  // RNE
  return (unsigned short)(u >> 16);
}

// Fused prep kernel, 1856 blocks:
//   blocks 0..1599: L2-normalize 6400 rows (4096 caption + 2304 image rows)
//     into MFMA fragment layout (1 row/wave, 4 rows/block).
//   blocks 1600..1855: Gram quadrants (4 blocks/image, 324 entries each),
//     normalized internally from raw f32 images, off-diag pre-doubled.
__global__ __launch_bounds__(256) void k_prep(const float* __restrict__ cap,
                                              const float* __restrict__ img,
                                              unsigned short* __restrict__ capT,
                                              unsigned short* __restrict__ imgT,
                                              float* __restrict__ G2) {
  __shared__ float si[RREG * GST + RREG];  // gram staging + invn
  int tid = threadIdx.x;
  int w = tid >> 6, lane = tid & 63;
  int bid = blockIdx.x;

  if (bid < 1600) {
    // ---- norm + fragment scatter ----
    int kkw = lane >> 2, kgw = lane & 3;  // lane's (kk, kg) in frag layout
    int v = bid * 4 + w;
    const float* p;
    unsigned short* dst;
    if (v < NCAP * LTOK) {
      int c = v >> 6, row = v & 63;
      int m = row >> 4, rqw = row & 15;
      p = cap + (size_t)v * EDIM + lane * 8;
      dst = capT + (size_t)c * 32768 +
            (size_t)(((m * 16 + kkw) * 64 + kgw * 16 + rqw) * 8);
    } else {
      int vi = v - NCAP * LTOK;
      int i = vi / RREG;
      int r = vi - i * RREG;
      p = img + ((size_t)i * RREG + r) * EDIM + lane * 8;
      if (r < 32) {
        int n = r >> 4, rqw = r & 15;
        dst = imgT + (size_t)i * IMGT_STRIDE +
              (size_t)(((n * 16 + kkw) * 64 + kgw * 16 + rqw) * 8);
      } else {
        int rq2 = r - 32;  // 0..3
        dst = imgT + (size_t)i * IMGT_STRIDE + 16384 +
              (size_t)(kkw * 128 + (kgw * 4 + rq2) * 8);
      }
    }
    float4 a = *(const float4*)p;
    float4 b = *(const float4*)(p + 4);
    float ss = a.x * a.x + a.y * a.y + a.z * a.z + a.w * a.w +
               b.x * b.x + b.y * b.y + b.z * b.z + b.w * b.w;
#pragma unroll
    for (int off = 1; off < 64; off <<= 1) ss += __shfl_xor(ss, off);
    float sc = 1.0f / fmaxf(sqrtf(ss), 1e-12f);
    u16x8 o = {f2bf(a.x * sc), f2bf(a.y * sc), f2bf(a.z * sc), f2bf(a.w * sc),
               f2bf(b.x * sc), f2bf(b.y * sc), f2bf(b.z * sc), f2bf(b.w * sc)};
    *(u16x8*)dst = o;
    return;
  }

  // ---- gram ----
  float* invn = si + RREG * GST;
  int qb = bid - 1600;
  int i = qb >> 2, q = qb & 3;
  const float* base = img + (size_t)i * RREG * EDIM;
  float acc[2] = {0.f, 0.f};
  float ssr[9];
#pragma unroll
  for (int t = 0; t < 9; ++t) ssr[t] = 0.f;

  for (int pass = 0; pass < 2; ++pass) {
    __syncthreads();
    for (int t = tid; t < RREG * 64; t += 256) {
      int row = t >> 6, e4 = t & 63;
      *(float4*)(si + row * GST + e4 * 4) =
          *(const float4*)(base + row * EDIM + pass * 256 + e4 * 4);
    }
    __syncthreads();
#pragma unroll
    for (int t = 0; t < 9; ++t) {
      int row = w + t * 4;
      float4 x = *(const float4*)(si + row * GST + lane * 4);
      ssr[t] += x.x * x.x + x.y * x.y + x.z * x.z + x.w * x.w;
    }
#pragma unroll
    for (int t = 0; t < 2; ++t) {
      int ofs = t * 256 + tid;
      if (ofs < 324) {
        int idx = q * 324 + ofs;
        int r = idx / 36, r2 = idx - r * 36;
        const float* pa = si + r * GST;
        const float* pb = si + r2 * GST;
        float a2 = acc[t];
#pragma unroll 8
        for (int e = 0; e < 256; e += 4) {
          float4 x = *(const float4*)(pa + e);
          float4 y = *(const float4*)(pb + e);
          a2 = fmaf(x.x, y.x, a2);
          a2 = fmaf(x.y, y.y, a2);
          a2 = fmaf(x.z, y.z, a2);
          a2 = fmaf(x.w, y.w, a2);
        }
        acc[t] = a2;
      }
    }
  }
#pragma unroll
  for (int t = 0; t < 9; ++t) {
    float ss = ssr[t];
#pragma unroll
    for (int off = 1; off < 64; off <<= 1) ss += __shfl_xor(ss, off);
    if (lane == 0) invn[w + t * 4] = 1.0f / fmaxf(sqrtf(ss), 1e-12f);
  }
  __syncthreads();
#pragma unroll
  for (int t = 0; t < 2; ++t) {
    int ofs = t * 256 + tid;
    if (ofs < 324) {
      int idx = q * 324 + ofs;
      int r = idx / 36, r2 = idx - r * 36;
      float vv = acc[t] * invn[r] * invn[r2];
      G2[(size_t)i * 1296 + idx] = (r == r2) ? vv : 2.0f * vv;
    }
  }
}

// ---------------- main fused kernel ----------------
// Block = (caption c, image-group of 4); wave w -> image i0+w.
// A staged per block into LDS (two 32KB K-halves, global_load_lds).
// B: explicit distance-3 register-ring prefetch (9 loads in flight/wave)
// from the pad-free imgT layout; n=2 frag cndmask-zeroed for lanes rq>=4.
__global__ __launch_bounds__(256, 4) void k_main(
    const unsigned short* __restrict__ capT,
    const unsigned short* __restrict__ imgT, const float* __restrict__ G2,
    const int* __restrict__ lens, float* __restrict__ out) {
  __shared__ __align__(16) float lds[4 * 64 * SSTR];  // 38912 B
  int tid = threadIdx.x;
  int w = tid >> 6, lane = tid & 63;
  int bid = blockIdx.x;
  int b = (bid & 7) * 128 + (bid >> 3);  // XCD-aware swizzle (1024 % 8 == 0)
  int c = b >> 4;
  int i = (b & 15) * 4 + w;
  int rq = lane & 15, kg = lane >> 4;

  const unsigned short* Acap = capT + (size_t)c * 32768;
  const unsigned short* B01 = imgT + (size_t)i * IMGT_STRIDE + lane * 8;
  const unsigned short* B2q =
      imgT + (size_t)i * IMGT_STRIDE + 16384 + (kg * 4 + (rq & 3)) * 8;
  char* ldsb = (char*)lds;
  bf16x8 zerov = {};

  f32x4 acc[4][3];
#pragma unroll
  for (int m = 0; m < 4; ++m)
#pragma unroll
    for (int n = 0; n < 3; ++n) acc[m][n] = 0.f;

  bf16x8 br[3][3];
#define LOADB(kk)                                                   \
  {                                                                 \
    br[(kk) % 3][0] = *(const bf16x8*)(B01 + (0 * 16 + (kk)) * 512); \
    br[(kk) % 3][1] = *(const bf16x8*)(B01 + (16 + (kk)) * 512);     \
    br[(kk) % 3][2] = *(const bf16x8*)(B2q + (kk) * 128);            \
  }

  // Stage A-half h: wave w stages m-tile w's 8 frags.
#define STAGE_A(h)                                                  \
  {                                                                 \
    _Pragma("unroll") for (int j = 0; j < 8; ++j) {                 \
      gl16(Acap + (size_t)(w * 16 + (h)*8 + j) * 512 + lane * 8,    \
           ldsb + (w * 8 + j) * 1024);                              \
    }                                                               \
  }

#define GEMM_STEP(kk, kkl)                                                   \
  {                                                                          \
    bf16x8 a0 = *(const bf16x8*)(ldsb + (0 * 8 + (kkl)) * 1024 + lane * 16); \
    bf16x8 a1 = *(const bf16x8*)(ldsb + (1 * 8 + (kkl)) * 1024 + lane * 16); \
    bf16x8 a2 = *(const bf16x8*)(ldsb + (2 * 8 + (kkl)) * 1024 + lane * 16); \
    bf16x8 a3 = *(const bf16x8*)(ldsb + (3 * 8 + (kkl)) * 1024 + lane * 16); \
    bf16x8 b0 = br[(kk) % 3][0];                                             \
    bf16x8 b1 = br[(kk) % 3][1];                                             \
    bf16x8 b2 = (rq < 4) ? br[(kk) % 3][2] : zerov;                          \
    acc[0][0] = __builtin_amdgcn_mfma_f32_16x16x32_bf16(a0, b0, acc[0][0], 0, 0, 0); \
    acc[0][1] = __builtin_amdgcn_mfma_f32_16x16x32_bf16(a0, b1, acc[0][1], 0, 0, 0); \
    acc[0][2] = __builtin_amdgcn_mfma_f32_16x16x32_bf16(a0, b2, acc[0][2], 0, 0, 0); \
    acc[1][0] = __builtin_amdgcn_mfma_f32_16x16x32_bf16(a1, b0, acc[1][0], 0, 0, 0); \
    acc[1][1] = __builtin_amdgcn_mfma_f32_16x16x32_bf16(a1, b1, acc[1][1], 0, 0, 0); \
    acc[1][2] = __builtin_amdgcn_mfma_f32_16x16x32_bf16(a1, b2, acc[1][2], 0, 0, 0); \
    acc[2][0] = __builtin_amdgcn_mfma_f32_16x16x32_bf16(a2, b0, acc[2][0], 0, 0, 0); \
    acc[2][1] = __builtin_amdgcn_mfma_f32_16x16x32_bf16(a2, b1, acc[2][1], 0, 0, 0); \
    acc[2][2] = __builtin_amdgcn_mfma_f32_16x16x32_bf16(a2, b2, acc[2][2], 0, 0, 0); \
    acc[3][0] = __builtin_amdgcn_mfma_f32_16x16x32_bf16(a3, b0, acc[3][0], 0, 0, 0); \
    acc[3][1] = __builtin_amdgcn_mfma_f32_16x16x32_bf16(a3, b1, acc[3][1], 0, 0, 0); \
    acc[3][2] = __builtin_amdgcn_mfma_f32_16x16x32_bf16(a3, b2, acc[3][2], 0, 0, 0); \
    if ((kk) + 3 < 16) LOADB((kk) + 3);                                      \
  }

  LOADB(0);
  LOADB(1);
  LOADB(2);
  STAGE_A(0);
  __syncthreads();
  GEMM_STEP(0, 0) GEMM_STEP(1, 1) GEMM_STEP(2, 2) GEMM_STEP(3, 3)
  GEMM_STEP(4, 4) GEMM_STEP(5, 5) GEMM_STEP(6, 6) GEMM_STEP(7, 7)
  __syncthreads();
  STAGE_A(1);
  __syncthreads();
  GEMM_STEP(8, 0) GEMM_STEP(9, 1) GEMM_STEP(10, 2) GEMM_STEP(11, 3)
  GEMM_STEP(12, 4) GEMM_STEP(13, 5) GEMM_STEP(14, 6) GEMM_STEP(15, 7)
  __syncthreads();

  // S exchange. D layout: col = lane&15, row = (lane>>4)*4 + j.
#pragma unroll
  for (int m = 0; m < 4; ++m)
#pragma unroll
    for (int n = 0; n < 3; ++n)
#pragma unroll
      for (int j = 0; j < 4; ++j)
        if (n < 2 || rq < 4)
          lds[(w * 64 + m * 16 + kg * 4 + j) * SSTR + n * 16 + rq] =
              acc[m][n][j];
  __syncthreads();

  // Epilogue: thread = (image w, token l = lane)
  const float* Srow = lds + (size_t)(w * 64 + lane) * SSTR;
  float s[36];
#pragma unroll
  for (int r2 = 0; r2 < 18; ++r2) {
    float2 x = *(const float2*)(Srow + r2 * 2);
    s[r2 * 2 + 0] = x.x;
    s[r2 * 2 + 1] = x.y;
  }
  float mx = s[0];
#pragma unroll
  for (int r = 1; r < 36; ++r) mx = fmaxf(mx, s[r]);
  float p[36];
  float sum = 0.f, dotp = 0.f;
#pragma unroll
  for (int r = 0; r < 36; ++r) {
    p[r] = __expf(LAM * (s[r] - mx));
    sum += p[r];
    dotp = fmaf(p[r], s[r], dotp);
  }
  // q2 = p^T G p via triangular loop (G2 has off-diag pre-doubled)
  int iu = __builtin_amdgcn_readfirstlane(i);
  const float* Gi = G2 + (size_t)iu * 1296;
  float q2 = 0.f;
#pragma unroll
  for (int r2 = 0; r2 < 36; ++r2) {
    float t = 0.f;
#pragma unroll
    for (int r = 0; r <= r2; ++r) t = fmaf(Gi[r2 * 36 + r], p[r], t);
    q2 = fmaf(t, p[r2], q2);
  }
  float inv = 1.0f / sum;
  float dn = dotp * inv;
  float nb = sqrtf(fmaxf(q2, 0.f)) * inv;
  float rcos = dn / fmaxf(nb, 1e-8f);
  int len = lens[c];
  float val = (lane < len) ? rcos : 0.f;
#pragma unroll
  for (int off = 1; off < 64; off <<= 1) val += __shfl_xor(val, off);
  if (lane == 0) out[c * 64 + i] = val * (1.0f / 64.0f);
}

extern "C" void kernel_launch(void* const* d_in, const int* in_sizes, int n_in,
                              void* d_out, int out_size, void* d_ws,
                              size_t ws_size, hipStream_t stream) {
  const float* images = (const float*)d_in[0];    // (64,36,512) f32
  const float* captions = (const float*)d_in[1];  // (64,64,512) f32
  const int* lens = (const int*)d_in[2];          // (64,)
  float* out = (float*)d_out;                     // (64,64) f32

  char* ws = (char*)d_ws;
  unsigned short* capT = (unsigned short*)ws;              // 4096*512*2 = 4 MB
  unsigned short* imgT = (unsigned short*)(ws + 4194304);  // 64*18432*2
  float* G = (float*)(ws + 4194304 + 2359296);             // 64*1296*4

  k_prep<<<1856, 256, 0, stream>>>(captions, images, capT, imgT, G);
  k_main<<<1024, 256, 0, stream>>>(capT, imgT, G, lens, out);
}

// Round 7
// 48.041 us; speedup vs baseline: 2.4045x; 1.0463x over previous
//
#include <hip/hip_runtime.h>
#include <stdint.h>

// Sizes (fixed by the problem)
#define NCAP 64
#define NIMG 64
#define LTOK 64
#define RREG 36
#define EDIM 512
#define LAM 9.0f
#define GST 260  // gram LDS row stride (floats)
#define SSTR 38  // S-exchange row stride (floats)

// imgT per-image layout (shorts): 32 full frags (n=0,1; 512 shorts each) at
// 0..16383, then 16 quarter-frags (n=2 rows 32..35; 128 shorts each) at
// 16384..18431. Per-image stride 18432 shorts = 36864 B.
#define IMGT_STRIDE 18432

// k_main chunk staging: A 16KB + B-full 16KB + B-quarter 2KB = 34KB
#define CHUNK_BYTES 34816
#define LDS_BYTES 77824  // = 8 pairs * 64 tok * 38 f32 (S) >= 2*CHUNK_BYTES

typedef __attribute__((ext_vector_type(8))) short bf16x8;
typedef __attribute__((ext_vector_type(4))) float f32x4;
typedef __attribute__((ext_vector_type(8))) unsigned short u16x8;

typedef const __attribute__((address_space(1))) void* gas1_t;
typedef __attribute__((address_space(3))) void* las3_t;

__device__ __forceinline__ void gl16(const void* g, void* l) {
  // stages 16B/lane: LDS dest = l + lane*16 (wave-uniform base), global src
  // is per-lane.
  __builtin_amdgcn_global_load_lds((gas1_t)g, (las3_t)l, 16, 0, 0);
}

__device__ __forceinline__ unsigned short f2bf(float f) {
  unsigned int u = __float_as_uint(f);
  u += 0x7FFFu + ((u >> 16) & 1u);  // RNE
  return (unsigned short)(u >> 16);
}

// Fused prep kernel, 2112 blocks:
//   blocks 0..1599: L2-normalize 6400 rows (4096 caption + 2304 image rows)
//     into MFMA fragment layout (1 row/wave).
//   blocks 1600..2111: Gram eighths (8 blocks/image, 162 entries each),
//     normalized internally from raw f32 images, off-diag pre-doubled.
__global__ __launch_bounds__(256) void k_prep(const float* __restrict__ cap,
                                              const float* __restrict__ img,
                                              unsigned short* __restrict__ capT,
                                              unsigned short* __restrict__ imgT,
                                              float* __restrict__ G2) {
  __shared__ float si[RREG * GST + RREG];  // gram staging + invn
  int tid = threadIdx.x;
  int w = tid >> 6, lane = tid & 63;
  int bid = blockIdx.x;

  if (bid < 1600) {
    // ---- norm + fragment scatter ----
    int kkw = lane >> 2, kgw = lane & 3;  // lane's (kk, kg) in frag layout
    int v = bid * 4 + w;
    const float* p;
    unsigned short* dst;
    if (v < NCAP * LTOK) {
      int c = v >> 6, row = v & 63;
      int m = row >> 4, rqw = row & 15;
      p = cap + (size_t)v * EDIM + lane * 8;
      dst = capT + (size_t)c * 32768 +
            (size_t)(((m * 16 + kkw) * 64 + kgw * 16 + rqw) * 8);
    } else {
      int vi = v - NCAP * LTOK;
      int i = vi / RREG;
      int r = vi - i * RREG;
      p = img + ((size_t)i * RREG + r) * EDIM + lane * 8;
      if (r < 32) {
        int n = r >> 4, rqw = r & 15;
        dst = imgT + (size_t)i * IMGT_STRIDE +
              (size_t)(((n * 16 + kkw) * 64 + kgw * 16 + rqw) * 8);
      } else {
        int rq2 = r - 32;  // 0..3
        dst = imgT + (size_t)i * IMGT_STRIDE + 16384 +
              (size_t)(kkw * 128 + (kgw * 4 + rq2) * 8);
      }
    }
    float4 a = *(const float4*)p;
    float4 b = *(const float4*)(p + 4);
    float ss = a.x * a.x + a.y * a.y + a.z * a.z + a.w * a.w +
               b.x * b.x + b.y * b.y + b.z * b.z + b.w * b.w;
#pragma unroll
    for (int off = 1; off < 64; off <<= 1) ss += __shfl_xor(ss, off);
    float sc = 1.0f / fmaxf(sqrtf(ss), 1e-12f);
    u16x8 o = {f2bf(a.x * sc), f2bf(a.y * sc), f2bf(a.z * sc), f2bf(a.w * sc),
               f2bf(b.x * sc), f2bf(b.y * sc), f2bf(b.z * sc), f2bf(b.w * sc)};
    *(u16x8*)dst = o;
    return;
  }

  // ---- gram (8 blocks/image) ----
  float* invn = si + RREG * GST;
  int qb = bid - 1600;
  int i = qb >> 3, q = qb & 7;
  const float* base = img + (size_t)i * RREG * EDIM;
  int idx = q * 162 + tid;  // tid<162 active
  int r = idx / 36, r2 = idx - r * 36;
  float accv = 0.f;
  float ssr[9];
#pragma unroll
  for (int t = 0; t < 9; ++t) ssr[t] = 0.f;

  for (int pass = 0; pass < 2; ++pass) {
    __syncthreads();
    for (int t = tid; t < RREG * 64; t += 256) {
      int row = t >> 6, e4 = t & 63;
      *(float4*)(si + row * GST + e4 * 4) =
          *(const float4*)(base + row * EDIM + pass * 256 + e4 * 4);
    }
    __syncthreads();
#pragma unroll
    for (int t = 0; t < 9; ++t) {
      int row = w + t * 4;
      float4 x = *(const float4*)(si + row * GST + lane * 4);
      ssr[t] += x.x * x.x + x.y * x.y + x.z * x.z + x.w * x.w;
    }
    if (tid < 162) {
      const float* pa = si + r * GST;
      const float* pb = si + r2 * GST;
      float a2 = accv;
#pragma unroll 8
      for (int e = 0; e < 256; e += 4) {
        float4 x = *(const float4*)(pa + e);
        float4 y = *(const float4*)(pb + e);
        a2 = fmaf(x.x, y.x, a2);
        a2 = fmaf(x.y, y.y, a2);
        a2 = fmaf(x.z, y.z, a2);
        a2 = fmaf(x.w, y.w, a2);
      }
      accv = a2;
    }
  }
#pragma unroll
  for (int t = 0; t < 9; ++t) {
    float ss = ssr[t];
#pragma unroll
    for (int off = 1; off < 64; off <<= 1) ss += __shfl_xor(ss, off);
    if (lane == 0) invn[w + t * 4] = 1.0f / fmaxf(sqrtf(ss), 1e-12f);
  }
  __syncthreads();
  if (tid < 162) {
    float vv = accv * invn[r] * invn[r2];
    G2[(size_t)i * 1296 + idx] = (r == r2) ? vv : 2.0f * vv;
  }
}

// Stage one 64-col K-chunk for 2 captions + 4 images into LDS buf.
// 34 gl16 ops split across 8 waves (wave-uniform t).
__device__ __forceinline__ void stage_chunk(const unsigned short* capT,
                                            const unsigned short* imgT,
                                            char* buf, int c0, int i0, int ch,
                                            int w, int lane) {
#pragma unroll
  for (int j = 0; j < 5; ++j) {
    int t = w + j * 8;
    if (t < 16) {
      // A frag: t = wcap*8 + m*2 + kk
      int wcap = t >> 3, m = (t >> 1) & 3, kk = t & 1;
      const unsigned short* src =
          capT + (size_t)(c0 + wcap) * 32768 +
          (size_t)((m * 16 + ch * 2 + kk) * 512) + lane * 8;
      gl16(src, buf + (wcap * 8 + m * 2 + kk) * 1024);
    } else if (t < 32) {
      // B full frag: u = kk*8 + i*2 + f
      int u = t - 16;
      int kk = u >> 3, i = (u >> 1) & 3, f = u & 1;
      const unsigned short* src =
          imgT + (size_t)(i0 + i) * IMGT_STRIDE +
          (size_t)((f * 16 + ch * 2 + kk) * 512) + lane * 8;
      gl16(src, buf + 16384 + ((kk * 4 + i) * 2 + f) * 1024);
    } else if (t < 34) {
      // combined quarter frag (4 images, per-lane scattered source)
      int kk = t - 32;
      const unsigned short* src =
          imgT + (size_t)(i0 + (lane >> 4)) * IMGT_STRIDE + 16384 +
          (ch * 2 + kk) * 128 + (lane & 15) * 8;
      gl16(src, buf + 32768 + kk * 1024);
    }
  }
}

// ---------------- main fused kernel ----------------
// Block = (2 captions, 4 images) = 8 pairs, 8 waves (512 thr); wave w ->
// pair (wc = w>>2, wi = w&3). Both A and B LDS-staged per 64-col K-chunk
// (double-buffered, stage-next-before-compute, 1 barrier/chunk). Per-pair
// L2 traffic 34KB (vs 52KB in the 1cx4i layout). S-exchange overlays the
// staging buffers; epilogue thread = (pair, token).
__global__ __launch_bounds__(512, 4) void k_main(
    const unsigned short* __restrict__ capT,
    const unsigned short* __restrict__ imgT, const float* __restrict__ G2,
    const int* __restrict__ lens, float* __restrict__ out) {
  __shared__ __align__(16) char lds[LDS_BYTES];
  int tid = threadIdx.x;
  int w = tid >> 6, lane = tid & 63;
  int wc = w >> 2, wi = w & 3;
  int rq = lane & 15, kg = lane >> 4;
  int bid = blockIdx.x;
  int b = (bid & 7) * 64 + (bid >> 3);  // XCD swizzle (512 % 8 == 0)
  int cg = b >> 4, ig = b & 15;
  int c0 = cg * 2, i0 = ig * 4;

  f32x4 acc[4][3];
#pragma unroll
  for (int m = 0; m < 4; ++m)
#pragma unroll
    for (int n = 0; n < 3; ++n) acc[m][n] = 0.f;

  stage_chunk(capT, imgT, lds, c0, i0, 0, w, lane);
  __syncthreads();
#pragma unroll
  for (int ch = 0; ch < 8; ++ch) {
    char* cur = lds + (ch & 1) * CHUNK_BYTES;
    if (ch < 7)
      stage_chunk(capT, imgT, lds + ((ch + 1) & 1) * CHUNK_BYTES, c0, i0,
                  ch + 1, w, lane);
#pragma unroll
    for (int kk = 0; kk < 2; ++kk) {
      bf16x8 a0 = *(const bf16x8*)(cur + (wc * 8 + 0 * 2 + kk) * 1024 + lane * 16);
      bf16x8 a1 = *(const bf16x8*)(cur + (wc * 8 + 1 * 2 + kk) * 1024 + lane * 16);
      bf16x8 a2 = *(const bf16x8*)(cur + (wc * 8 + 2 * 2 + kk) * 1024 + lane * 16);
      bf16x8 a3 = *(const bf16x8*)(cur + (wc * 8 + 3 * 2 + kk) * 1024 + lane * 16);
      bf16x8 b0 = *(const bf16x8*)(cur + 16384 + ((kk * 4 + wi) * 2 + 0) * 1024 + lane * 16);
      bf16x8 b1 = *(const bf16x8*)(cur + 16384 + ((kk * 4 + wi) * 2 + 1) * 1024 + lane * 16);
      // quarter frag: cols 32..35; lanes rq>=4 read duplicate data whose
      // MFMA output cols (36..47) are never stored -> no masking needed.
      bf16x8 b2 = *(const bf16x8*)(cur + 32768 + kk * 1024 + wi * 256 +
                                   (kg * 4 + (rq & 3)) * 16);

      acc[0][0] = __builtin_amdgcn_mfma_f32_16x16x32_bf16(a0, b0, acc[0][0], 0, 0, 0);
      acc[0][1] = __builtin_amdgcn_mfma_f32_16x16x32_bf16(a0, b1, acc[0][1], 0, 0, 0);
      acc[0][2] = __builtin_amdgcn_mfma_f32_16x16x32_bf16(a0, b2, acc[0][2], 0, 0, 0);
      acc[1][0] = __builtin_amdgcn_mfma_f32_16x16x32_bf16(a1, b0, acc[1][0], 0, 0, 0);
      acc[1][1] = __builtin_amdgcn_mfma_f32_16x16x32_bf16(a1, b1, acc[1][1], 0, 0, 0);
      acc[1][2] = __builtin_amdgcn_mfma_f32_16x16x32_bf16(a1, b2, acc[1][2], 0, 0, 0);
      acc[2][0] = __builtin_amdgcn_mfma_f32_16x16x32_bf16(a2, b0, acc[2][0], 0, 0, 0);
      acc[2][1] = __builtin_amdgcn_mfma_f32_16x16x32_bf16(a2, b1, acc[2][1], 0, 0, 0);
      acc[2][2] = __builtin_amdgcn_mfma_f32_16x16x32_bf16(a2, b2, acc[2][2], 0, 0, 0);
      acc[3][0] = __builtin_amdgcn_mfma_f32_16x16x32_bf16(a3, b0, acc[3][0], 0, 0, 0);
      acc[3][1] = __builtin_amdgcn_mfma_f32_16x16x32_bf16(a3, b1, acc[3][1], 0, 0, 0);
      acc[3][2] = __builtin_amdgcn_mfma_f32_16x16x32_bf16(a3, b2, acc[3][2], 0, 0, 0);
    }
    __syncthreads();
  }

  // S exchange (overlays staging). D layout: col = lane&15, row=(lane>>4)*4+j.
  float* Sf = (float*)lds;
#pragma unroll
  for (int m = 0; m < 4; ++m)
#pragma unroll
    for (int n = 0; n < 3; ++n)
#pragma unroll
      for (int j = 0; j < 4; ++j)
        if (n < 2 || rq < 4)
          Sf[(w * 64 + m * 16 + kg * 4 + j) * SSTR + n * 16 + rq] =
              acc[m][n][j];
  __syncthreads();

  // Epilogue: thread = (pair w, token lane)
  int c = c0 + (w >> 2);
  int i = i0 + (w & 3);
  const float* Srow = Sf + (size_t)(w * 64 + lane) * SSTR;
  float s[36];
#pragma unroll
  for (int r2 = 0; r2 < 18; ++r2) {
    float2 x = *(const float2*)(Srow + r2 * 2);
    s[r2 * 2 + 0] = x.x;
    s[r2 * 2 + 1] = x.y;
  }
  float mx = s[0];
#pragma unroll
  for (int r = 1; r < 36; ++r) mx = fmaxf(mx, s[r]);
  float p[36];
  float sum = 0.f, dotp = 0.f;
#pragma unroll
  for (int r = 0; r < 36; ++r) {
    p[r] = __expf(LAM * (s[r] - mx));
    sum += p[r];
    dotp = fmaf(p[r], s[r], dotp);
  }
  // q2 = p^T G p via triangular loop (G2 has off-diag pre-doubled)
  int iu = __builtin_amdgcn_readfirstlane(i);
  const float* Gi = G2 + (size_t)iu * 1296;
  float q2 = 0.f;
#pragma unroll
  for (int r2 = 0; r2 < 36; ++r2) {
    float t = 0.f;
#pragma unroll
    for (int r = 0; r <= r2; ++r) t = fmaf(Gi[r2 * 36 + r], p[r], t);
    q2 = fmaf(t, p[r2], q2);
  }
  float inv = 1.0f / sum;
  float dn = dotp * inv;
  float nb = sqrtf(fmaxf(q2, 0.f)) * inv;
  float rcos = dn / fmaxf(nb, 1e-8f);
  int len = lens[c];
  float val = (lane < len) ? rcos : 0.f;
#pragma unroll
  for (int off = 1; off < 64; off <<= 1) val += __shfl_xor(val, off);
  if (lane == 0) out[c * 64 + i] = val * (1.0f / 64.0f);
}

extern "C" void kernel_launch(void* const* d_in, const int* in_sizes, int n_in,
                              void* d_out, int out_size, void* d_ws,
                              size_t ws_size, hipStream_t stream) {
  const float* images = (const float*)d_in[0];    // (64,36,512) f32
  const float* captions = (const float*)d_in[1];  // (64,64,512) f32
  const int* lens = (const int*)d_in[2];          // (64,)
  float* out = (float*)d_out;                     // (64,64) f32

  char* ws = (char*)d_ws;
  unsigned short* capT = (unsigned short*)ws;              // 4096*512*2 = 4 MB
  unsigned short* imgT = (unsigned short*)(ws + 4194304);  // 64*18432*2
  float* G = (float*)(ws + 4194304 + 2359296);             // 64*1296*4

  k_prep<<<2112, 256, 0, stream>>>(captions, images, capT, imgT, G);
  k_main<<<512, 512, 0, stream>>>(capT, imgT, G, lens, out);
}